// Round 1
// baseline (142.345 us; speedup 1.0000x reference)
//
#include <hip/hip_runtime.h>

#define KANCH 10
#define WIDTH 1024
#define CHAN  (5 * KANCH)

__device__ __forceinline__ float smooth_l1(float d) {
    float a = fabsf(d);
    return (a < 1.0f) ? (0.5f * a * a) : (a - 0.5f);
}

// stable log(exp(a)+exp(b)) == jnp.logaddexp
__device__ __forceinline__ float logaddexp_f(float a, float b) {
    float m = fmaxf(a, b);
    float n = fminf(a, b);
    return m + log1pf(expf(n - m));
}

__global__ __launch_bounds__(64) void ctpn_loss_kernel(
    const float* __restrict__ x,
    const float* __restrict__ v_targets,
    const float* __restrict__ o_targets,
    const int* __restrict__ pos_y, const int* __restrict__ pos_x, const int* __restrict__ pos_z,
    const int* __restrict__ neg_y, const int* __restrict__ neg_x, const int* __restrict__ neg_z,
    const void* __restrict__ o_mask,
    float* __restrict__ out,
    int Np, int Nn)
{
    const int lane = threadIdx.x;  // exactly 64 threads, one wave

    // ---- o_mask layout detection (bool dtype; device layout unspecified) ----
    // Safe: reading 64 bytes is in-bounds for every candidate layout (Np=64).
    unsigned char b8 = 0;
    if (lane < Np) b8 = ((const unsigned char*)o_mask)[lane];
    unsigned long long nz = __ballot(b8 != 0);

    bool maskBit = false;
    if (lane < Np) {
        if (!(nz & 1ULL)) {
            // element 0 is guaranteed True; low byte 0 only if fp32 (1.0f -> 00 00 80 3f)
            maskBit = (((const float*)o_mask)[lane] != 0.0f);
        } else if (nz & 0xEEEEEEEEEEEEEEEEULL) {
            // nonzero bytes off 4-byte alignment -> 1-byte bool storage
            maskBit = (b8 != 0);
        } else if (nz & 0x1010101010101010ULL) {
            // nonzero low bytes at 4 mod 8 -> int32 storage
            maskBit = (((const int*)o_mask)[lane] != 0);
        } else {
            // bits only at multiples of 8 -> int64 storage
            maskBit = (((const long long*)o_mask)[lane] != 0LL);
        }
    }

    float ce = 0.0f, lv = 0.0f, lo = 0.0f, cnt = 0.0f;

    // ---- positive anchors: CE(label=1), vertical SmoothL1, side refinement ----
    if (lane < Np) {
        int py = pos_y[lane], px = pos_x[lane], pz = pos_z[lane];
        const float* base = x + ((size_t)py * WIDTH + (size_t)px) * CHAN;

        float p0 = base[2 * KANCH + 2 * pz];
        float p1 = base[2 * KANCH + 2 * pz + 1];
        ce += logaddexp_f(p0, p1) - p1;

        float v0 = base[2 * pz];
        float v1 = base[2 * pz + 1];
        lv = 0.5f * (smooth_l1(v0 - v_targets[2 * lane]) +
                     smooth_l1(v1 - v_targets[2 * lane + 1]));

        float op = base[4 * KANCH + pz];
        float l  = smooth_l1(op - o_targets[lane]);
        lo  = maskBit ? l : 0.0f;
        cnt = maskBit ? 1.0f : 0.0f;
    }

    // ---- negative anchors: CE(label=0) ----
    if (lane < Nn) {
        int ny = neg_y[lane], nx = neg_x[lane], nzv = neg_z[lane];
        const float* base = x + ((size_t)ny * WIDTH + (size_t)nx) * CHAN;
        float n0 = base[2 * KANCH + 2 * nzv];
        float n1 = base[2 * KANCH + 2 * nzv + 1];
        ce += logaddexp_f(n0, n1) - n0;
    }

    // ---- single-wave butterfly reduction ----
    #pragma unroll
    for (int off = 32; off > 0; off >>= 1) {
        ce  += __shfl_xor(ce,  off, 64);
        lv  += __shfl_xor(lv,  off, 64);
        lo  += __shfl_xor(lo,  off, 64);
        cnt += __shfl_xor(cnt, off, 64);
    }

    if (lane == 0) {
        float loss_cls = ce / (float)(Np + Nn);
        float n_o = cnt;  // >= 1 guaranteed by the harness (o_mask[0] = True)
        out[0] = loss_cls + (lv + lo) / n_o;
    }
}

extern "C" void kernel_launch(void* const* d_in, const int* in_sizes, int n_in,
                              void* d_out, int out_size, void* d_ws, size_t ws_size,
                              hipStream_t stream) {
    const float* x   = (const float*)d_in[0];
    const float* vt  = (const float*)d_in[1];
    const float* ot  = (const float*)d_in[2];
    const int* py    = (const int*)d_in[3];
    const int* px    = (const int*)d_in[4];
    const int* pz    = (const int*)d_in[5];
    const int* ny    = (const int*)d_in[6];
    const int* nx    = (const int*)d_in[7];
    const int* nz    = (const int*)d_in[8];
    const void* om   = d_in[9];
    float* out       = (float*)d_out;

    int Np = in_sizes[3];  // pos_y length (= 64)
    int Nn = in_sizes[6];  // neg_y length (= 64)

    hipLaunchKernelGGL(ctpn_loss_kernel, dim3(1), dim3(64), 0, stream,
                       x, vt, ot, py, px, pz, ny, nx, nz, om, out, Np, Nn);
}